// Round 12
// baseline (8435.265 us; speedup 1.0000x reference)
//
#include <hip/hip_runtime.h>
#include <math.h>

#define NB 16
#define CB 256
#define MIP 8
#define EPSV 1e-5f
#define GRID 512   // 2 blocks/CU; launch_bounds(256,4) => capacity 4/CU (2x margin)

// Pipelined persistent kernel. Block b owns (c = b>>1, half = b&1):
// for each image n: R(n) [reduce its half-plane], last-finisher does M(n),
// then A(n-1) gated on flag[n-1]. A re-reads the half-plane this same CU
// streamed one image-step earlier (L2-hot), overlapping with other blocks' R.
__global__ __launch_bounds__(256, 4) void k_pipe(
    const float* __restrict__ x, const float* __restrict__ res,
    const float* __restrict__ w1, const float* __restrict__ b1,
    const float* __restrict__ gamma, const float* __restrict__ beta,
    const float* __restrict__ mean, const float* __restrict__ var,
    const float* __restrict__ w2, const float* __restrict__ b2,
    const float* __restrict__ w3, const float* __restrict__ b3,
    float* __restrict__ out,
    float* __restrict__ xh, float* __restrict__ xwA, float* __restrict__ xwB,
    float* __restrict__ yl,
    unsigned* __restrict__ cnt, unsigned* __restrict__ flag)
{
    const int b    = blockIdx.x;
    const int t    = threadIdx.x;
    const int half = b & 1;
    const int c    = b >> 1;
    float* xwH = half ? xwB : xwA;

    __shared__ float spad[256];
    __shared__ float sah[32];
    __shared__ float saw[64];
    __shared__ int   lastf;

    const int wv  = t >> 6;
    const int l16 = t & 15;
    const int g16 = (t >> 4) & 3;   // row sub-group within wave (0..3)
    const int g16f = t >> 4;        // 0..15 across block

    for (int n = 0; n < NB; ++n) {
        // ---------------- R(n): reduce this half-plane ----------------
        {
            size_t plane = (size_t)n * CB + c;
            const float4* px4 = (const float4*)x   + plane * 1024 + half * 512;
            const float4* pr4 = (const float4*)res + plane * 1024 + half * 512;
            float4 a0 = px4[t], a1 = px4[256 + t];
            float4 r0 = pr4[t], r1 = pr4[256 + t];
            float s00=a0.x+r0.x, s01=a0.y+r0.y, s02=a0.z+r0.z, s03=a0.w+r0.w;
            float s10=a1.x+r1.x, s11=a1.y+r1.y, s12=a1.z+r1.z, s13=a1.w+r1.w;
            // row sums (full 64-wide rows: 16 lanes x 4 floats)
            float rs0 = (s00+s01)+(s02+s03);
            float rs1 = (s10+s11)+(s12+s13);
            rs0 += __shfl_xor(rs0,1); rs0 += __shfl_xor(rs0,2);
            rs0 += __shfl_xor(rs0,4); rs0 += __shfl_xor(rs0,8);
            rs1 += __shfl_xor(rs1,1); rs1 += __shfl_xor(rs1,2);
            rs1 += __shfl_xor(rs1,4); rs1 += __shfl_xor(rs1,8);
            if (l16 == 0) {
                xh[plane*64 + half*32 +      g16f] = rs0 * 0.015625f;
                xh[plane*64 + half*32 + 16 + g16f] = rs1 * 0.015625f;
            }
            // col partial sums over this half's 32 rows
            float c0 = s00+s10, c1 = s01+s11, c2 = s02+s12, c3 = s03+s13;
            c0 += __shfl_xor(c0,16); c0 += __shfl_xor(c0,32);
            c1 += __shfl_xor(c1,16); c1 += __shfl_xor(c1,32);
            c2 += __shfl_xor(c2,16); c2 += __shfl_xor(c2,32);
            c3 += __shfl_xor(c3,16); c3 += __shfl_xor(c3,32);
            if ((t & 63) < 16) {
                float* d = &spad[wv*64 + l16*4];
                d[0]=c0; d[1]=c1; d[2]=c2; d[3]=c3;
            }
            __syncthreads();
            if (t < 64)
                xwH[plane*64 + t] = spad[t]+spad[64+t]+spad[128+t]+spad[192+t];
            __threadfence();
            __syncthreads();
            if (t == 0) {
                unsigned old = atomicAdd(&cnt[n], 1u);
                lastf = (old == GRID - 1) ? 1 : 0;
            }
            __syncthreads();
        }
        // ---------------- M(n) by the last finisher ----------------
        if (lastf) {
            __threadfence();
            int p  = t & 127;
            int mg = (t >> 7) * 4;
            float acc0=0.f, acc1=0.f, acc2=0.f, acc3=0.f;
            const float* w1r0 = w1 + (mg+0)*CB;
            const float* w1r1 = w1 + (mg+1)*CB;
            const float* w1r2 = w1 + (mg+2)*CB;
            const float* w1r3 = w1 + (mg+3)*CB;
            for (int cc = 0; cc < CB; ++cc) {
                size_t pl = (size_t)n * CB + cc;
                float pv;
                if (p < 64) pv = xh[pl*64 + p];
                else pv = (xwA[pl*64 + (p-64)] + xwB[pl*64 + (p-64)]) * 0.015625f;
                acc0 += pv * w1r0[cc];
                acc1 += pv * w1r1[cc];
                acc2 += pv * w1r2[cc];
                acc3 += pv * w1r3[cc];
            }
            float a4[4] = {acc0,acc1,acc2,acc3};
#pragma unroll
            for (int k = 0; k < 4; ++k) {
                int m = mg + k;
                float yv = a4[k] + b1[m];
                float inv = gamma[m] * rsqrtf(var[m] + EPSV);
                yv = (yv - mean[m]) * inv + beta[m];
                float cl = fminf(fmaxf(yv + 3.f, 0.f), 6.f);
                yl[(size_t)n*1024 + m*128 + p] = yv * cl * (1.f/6.f);
            }
            __threadfence();
            __syncthreads();
            if (t == 0)
                __hip_atomic_store(&flag[n], 1u, __ATOMIC_RELEASE,
                                   __HIP_MEMORY_SCOPE_AGENT);
        }
        // ---------------- A(n-1) ----------------
        if (n >= 1) {
            int ni = n - 1;
            if (t == 0) {
                while (__hip_atomic_load(&flag[ni], __ATOMIC_ACQUIRE,
                                         __HIP_MEMORY_SCOPE_AGENT) == 0u)
                    __builtin_amdgcn_s_sleep(8);
            }
            __syncthreads();
            if (t < 32) {
                int h = half*32 + t;
                float acc = b2[c];
#pragma unroll
                for (int m = 0; m < MIP; ++m)
                    acc += w2[c*MIP+m] * yl[(size_t)ni*1024 + m*128 + h];
                sah[t] = 1.f/(1.f+__expf(-acc));
            } else if (t < 96) {
                int w = t - 32;
                float acc = b3[c];
#pragma unroll
                for (int m = 0; m < MIP; ++m)
                    acc += w3[c*MIP+m] * yl[(size_t)ni*1024 + m*128 + 64 + w];
                saw[w] = 1.f/(1.f+__expf(-acc));
            }
            __syncthreads();
            size_t plane = (size_t)ni * CB + c;
            const float4* px4 = (const float4*)x   + plane*1024 + half*512;
            const float4* pr4 = (const float4*)res + plane*1024 + half*512;
            float4*       po4 = (float4*)out       + plane*1024 + half*512;
            const float4 sw4 = *(const float4*)&saw[4*l16];
#pragma unroll
            for (int j = 0; j < 2; ++j) {
                float ah2 = 2.f * sah[j*16 + g16f];
                float4 a = px4[j*256+t];
                float4 r = pr4[j*256+t];
                float4 o;
                o.x = a.x*(ah2*sw4.x) + 2.f*r.x;
                o.y = a.y*(ah2*sw4.y) + 2.f*r.y;
                o.z = a.z*(ah2*sw4.z) + 2.f*r.z;
                o.w = a.w*(ah2*sw4.w) + 2.f*r.w;
                po4[j*256+t] = o;
            }
            __syncthreads();
        }
    }
    // ---------------- A(15) ----------------
    {
        int ni = NB - 1;
        if (t == 0) {
            while (__hip_atomic_load(&flag[ni], __ATOMIC_ACQUIRE,
                                     __HIP_MEMORY_SCOPE_AGENT) == 0u)
                __builtin_amdgcn_s_sleep(8);
        }
        __syncthreads();
        if (t < 32) {
            int h = half*32 + t;
            float acc = b2[c];
#pragma unroll
            for (int m = 0; m < MIP; ++m)
                acc += w2[c*MIP+m] * yl[(size_t)ni*1024 + m*128 + h];
            sah[t] = 1.f/(1.f+__expf(-acc));
        } else if (t < 96) {
            int w = t - 32;
            float acc = b3[c];
#pragma unroll
            for (int m = 0; m < MIP; ++m)
                acc += w3[c*MIP+m] * yl[(size_t)ni*1024 + m*128 + 64 + w];
            saw[w] = 1.f/(1.f+__expf(-acc));
        }
        __syncthreads();
        size_t plane = (size_t)ni * CB + c;
        const float4* px4 = (const float4*)x   + plane*1024 + half*512;
        const float4* pr4 = (const float4*)res + plane*1024 + half*512;
        float4*       po4 = (float4*)out       + plane*1024 + half*512;
        const float4 sw4 = *(const float4*)&saw[4*l16];
#pragma unroll
        for (int j = 0; j < 2; ++j) {
            float ah2 = 2.f * sah[j*16 + g16f];
            float4 a = px4[j*256+t];
            float4 r = pr4[j*256+t];
            float4 o;
            o.x = a.x*(ah2*sw4.x) + 2.f*r.x;
            o.y = a.y*(ah2*sw4.y) + 2.f*r.y;
            o.z = a.z*(ah2*sw4.z) + 2.f*r.z;
            o.w = a.w*(ah2*sw4.w) + 2.f*r.w;
            po4[j*256+t] = o;
        }
    }
}

extern "C" void kernel_launch(void* const* d_in, const int* in_sizes, int n_in,
                              void* d_out, int out_size, void* d_ws, size_t ws_size,
                              hipStream_t stream) {
    const float* x     = (const float*)d_in[0];
    const float* res   = (const float*)d_in[1];
    const float* w1    = (const float*)d_in[2];
    const float* b1    = (const float*)d_in[3];
    const float* gamma = (const float*)d_in[4];
    const float* beta  = (const float*)d_in[5];
    const float* mean  = (const float*)d_in[6];
    const float* var   = (const float*)d_in[7];
    const float* w2    = (const float*)d_in[8];
    const float* b2    = (const float*)d_in[9];
    const float* w3    = (const float*)d_in[10];
    const float* b3    = (const float*)d_in[11];
    float* out = (float*)d_out;

    float* ws = (float*)d_ws;
    float* xh  = ws;                        // 4096*64
    float* xwA = ws + 262144;               // 4096*64 (rows 0..31 partials)
    float* xwB = ws + 524288;               // 4096*64 (rows 32..63 partials)
    float* yl  = ws + 786432;               // 16*8*128
    unsigned* cnt  = (unsigned*)(ws + 802816);  // 16
    unsigned* flag = cnt + 16;                  // 16

    hipMemsetAsync(cnt, 0, 128, stream);
    k_pipe<<<GRID, 256, 0, stream>>>(x, res, w1, b1, gamma, beta, mean, var,
                                     w2, b2, w3, b3, out, xh, xwA, xwB, yl,
                                     cnt, flag);
}

// Round 13
// 56.998 us; speedup vs baseline: 147.9936x; 147.9936x over previous
//
#include <hip/hip_runtime.h>
#include <math.h>

#define NB 16
#define CB 256
#define MIP 8
#define EPSV 1e-5f

// K1: per (n,c) plane: row means -> xh, col means -> xw.  Zig-zag plane order
// (descending within XCD) for the L2 handoff with k_apply (ascending).
// PROBE: x staged via global_load_lds DMA (separate return path?), res via
// VGPR loads — tests whether the two paths have independent outstanding-miss
// pools. Reduction math identical to R11.
__global__ __launch_bounds__(256) void k_reduce(const float* __restrict__ x,
                                                const float* __restrict__ res,
                                                float* __restrict__ xh,
                                                float* __restrict__ xw) {
    int bid = blockIdx.x;
    int plane = (bid & 7) + 8 * (511 - (bid >> 3));   // same XCD, reversed order
    const float4* px4 = (const float4*)(x   + (size_t)plane * 4096);
    const float4* pr4 = (const float4*)(res + (size_t)plane * 4096);
    __shared__ float4 lx4[1024];                      // 16 KB staged x-plane
    __shared__ float spad[256];
    int t = threadIdx.x;
    int w = t >> 6;                                   // wave 0..3
    int l = t & 63;

#if __has_builtin(__builtin_amdgcn_global_load_lds)
#pragma unroll
    for (int i = 0; i < 4; i++) {
        const float4* g = &px4[i * 256 + w * 64 + l]; // per-lane global src
        void* ldst = (void*)&lx4[i * 256 + w * 64];   // wave-uniform LDS base
        __builtin_amdgcn_global_load_lds(
            (const __attribute__((address_space(1))) void*)g,
            (__attribute__((address_space(3))) void*)ldst, 16, 0, 0);
    }
#else
#pragma unroll
    for (int i = 0; i < 4; i++) lx4[i * 256 + t] = px4[i * 256 + t];
#endif

    // res via the VGPR-return path, overlapping the DMA
    float4 b[4];
#pragma unroll
    for (int i = 0; i < 4; i++) b[i] = pr4[i * 256 + t];

    __builtin_amdgcn_s_waitcnt(0);                    // drain vm+lgkm for this wave
    __syncthreads();

    float4 a[4];
#pragma unroll
    for (int i = 0; i < 4; i++) a[i] = lx4[i * 256 + t];

    float csum0 = 0.f, csum1 = 0.f, csum2 = 0.f, csum3 = 0.f;
    float rsum[4];
#pragma unroll
    for (int i = 0; i < 4; i++) {
        float s0 = a[i].x + b[i].x, s1 = a[i].y + b[i].y;
        float s2 = a[i].z + b[i].z, s3 = a[i].w + b[i].w;
        csum0 += s0; csum1 += s1; csum2 += s2; csum3 += s3;
        rsum[i] = (s0 + s1) + (s2 + s3);
    }
#pragma unroll
    for (int i = 0; i < 4; i++) {
        float rs = rsum[i];
        rs += __shfl_xor(rs, 1);
        rs += __shfl_xor(rs, 2);
        rs += __shfl_xor(rs, 4);
        rs += __shfl_xor(rs, 8);
        rsum[i] = rs;
    }
    if ((t & 15) == 0) {
        int g = t >> 4;
#pragma unroll
        for (int i = 0; i < 4; i++)
            xh[(size_t)plane * 64 + i * 16 + g] = rsum[i] * 0.015625f;
    }
    csum0 += __shfl_xor(csum0, 16); csum0 += __shfl_xor(csum0, 32);
    csum1 += __shfl_xor(csum1, 16); csum1 += __shfl_xor(csum1, 32);
    csum2 += __shfl_xor(csum2, 16); csum2 += __shfl_xor(csum2, 32);
    csum3 += __shfl_xor(csum3, 16); csum3 += __shfl_xor(csum3, 32);
    int wv = t >> 6;
    int j  = t & 15;
    if ((t & 63) < 16) {
        float* d = &spad[wv * 64 + j * 4];
        d[0] = csum0; d[1] = csum1; d[2] = csum2; d[3] = csum3;
    }
    __syncthreads();
    if (t < 64)
        xw[(size_t)plane * 64 + t] =
            (spad[t] + spad[64 + t] + spad[128 + t] + spad[192 + t]) * 0.015625f;
}

// K2: grid = NB*8 blocks. Block (n, pc) covers p in [pc*16, pc*16+16).
__global__ __launch_bounds__(256) void k_mid(const float* __restrict__ xh,
                                             const float* __restrict__ xw,
                                             const float* __restrict__ w1,
                                             const float* __restrict__ b1,
                                             const float* __restrict__ gamma,
                                             const float* __restrict__ beta,
                                             const float* __restrict__ mean,
                                             const float* __restrict__ var,
                                             const float* __restrict__ w2,
                                             const float* __restrict__ b2,
                                             const float* __restrict__ w3,
                                             const float* __restrict__ b3,
                                             float* __restrict__ ah,
                                             float* __restrict__ aw) {
    int n  = blockIdx.x >> 3;
    int pc = blockIdx.x & 7;
    int t  = threadIdx.x;
    int ph = t & 15;
    int p  = pc * 16 + ph;
    int m  = (t >> 4) & 7;
    int half = t >> 7;
    __shared__ float part[256];
    __shared__ float ylds[MIP * 16];

    const float* pool = (p < 64) ? (xh + ((size_t)n * CB) * 64 + p)
                                 : (xw + ((size_t)n * CB) * 64 + (p - 64));
    float acc = 0.f;
    int c0 = half * 128;
#pragma unroll 16
    for (int ci = 0; ci < 128; ci++) {
        int c = c0 + ci;
        acc += pool[(size_t)c * 64] * w1[m * CB + c];
    }
    part[t] = acc;
    __syncthreads();
    if (t < 128) {
        float val = part[t] + part[t + 128] + b1[m];
        float inv = gamma[m] * rsqrtf(var[m] + EPSV);
        val = (val - mean[m]) * inv + beta[m];
        float cl = fminf(fmaxf(val + 3.f, 0.f), 6.f);
        ylds[m * 16 + ph] = val * cl * (1.f / 6.f);
    }
    __syncthreads();

    const float* wsel = (p < 64) ? w2 : w3;
    const float* bsel = (p < 64) ? b2 : b3;
    float* osel = (p < 64) ? (ah + ((size_t)n * CB) * 64 + p)
                           : (aw + ((size_t)n * CB) * 64 + (p - 64));
#pragma unroll
    for (int oo = 0; oo < 16; oo++) {
        int o = oo * 16 + (t >> 4);
        float acc2 = bsel[o];
#pragma unroll
        for (int mm = 0; mm < MIP; mm++)
            acc2 += wsel[o * MIP + mm] * ylds[mm * 16 + ph];
        osel[(size_t)o * 64] = 1.f / (1.f + __expf(-acc2));
    }
}

// K3: per (n,o) plane: load ah/aw, out = 2*wei*x + 2*res.  Ascending order.
__global__ __launch_bounds__(256) void k_apply(const float* __restrict__ x,
                                               const float* __restrict__ res,
                                               const float* __restrict__ ah,
                                               const float* __restrict__ aw,
                                               float* __restrict__ out) {
    int plane = blockIdx.x;
    const float4* px4 = (const float4*)(x   + (size_t)plane * 4096);
    const float4* pr4 = (const float4*)(res + (size_t)plane * 4096);
    float4*       po4 = (float4*)(out + (size_t)plane * 4096);
    __shared__ float sah[64], saw[64];
    int t = threadIdx.x;
    if (t < 64)       sah[t]      = ah[(size_t)plane * 64 + t];
    else if (t < 128) saw[t - 64] = aw[(size_t)plane * 64 + (t - 64)];
    __syncthreads();
    const float4 sw4 = *(const float4*)&saw[4 * (t & 15)];
#pragma unroll
    for (int i = 0; i < 4; i++) {
        int row = i * 16 + (t >> 4);
        float ahr2 = 2.f * sah[row];
        float4 a = px4[i * 256 + t];
        float4 b = pr4[i * 256 + t];
        float4 oo;
        oo.x = a.x * (ahr2 * sw4.x) + 2.f * b.x;
        oo.y = a.y * (ahr2 * sw4.y) + 2.f * b.y;
        oo.z = a.z * (ahr2 * sw4.z) + 2.f * b.z;
        oo.w = a.w * (ahr2 * sw4.w) + 2.f * b.w;
        po4[i * 256 + t] = oo;
    }
}

extern "C" void kernel_launch(void* const* d_in, const int* in_sizes, int n_in,
                              void* d_out, int out_size, void* d_ws, size_t ws_size,
                              hipStream_t stream) {
    const float* x     = (const float*)d_in[0];
    const float* res   = (const float*)d_in[1];
    const float* w1    = (const float*)d_in[2];
    const float* b1    = (const float*)d_in[3];
    const float* gamma = (const float*)d_in[4];
    const float* beta  = (const float*)d_in[5];
    const float* mean  = (const float*)d_in[6];
    const float* var   = (const float*)d_in[7];
    const float* w2    = (const float*)d_in[8];
    const float* b2    = (const float*)d_in[9];
    const float* w3    = (const float*)d_in[10];
    const float* b3    = (const float*)d_in[11];
    float* out = (float*)d_out;

    float* ws = (float*)d_ws;
    float* xh = ws;                 // 16*256*64 = 262144 floats
    float* xw = ws + 262144;
    float* ah = ws + 524288;
    float* aw = ws + 786432;        // total 4 MiB

    k_reduce<<<NB * CB, 256, 0, stream>>>(x, res, xh, xw);
    k_mid<<<NB * 8, 256, 0, stream>>>(xh, xw, w1, b1, gamma, beta, mean, var,
                                      w2, b2, w3, b3, ah, aw);
    k_apply<<<NB * CB, 256, 0, stream>>>(x, res, ah, aw, out);
}